// Round 5
// baseline (393.868 us; speedup 1.0000x reference)
//
#include <hip/hip_runtime.h>
#include <math.h>

#define DD   128
#define KK   1024
#define HWW  4096
#define NPIX 131072
#define EPS  1.5e-4f        // >= 3.8x the ~3.9e-5 worst-case pair-comparison bound
#define CAPA 32768
#define CAPB 8192

// ws layout in float slots:
#define WS_WT    0           // fp32 wT[K][D]            131072
#define WS_E2    131072      // fp32 e2[K]                 1024
#define WS_CTR   132096      // int ctrA, ctrB (pad 64)
#define WS_LISTA 132160      // int {p,k1,k2} x CAPA      98304
#define WS_LISTB 230464      // int {p} x CAPB            16384
#define WS_BHI   246848      // bf16 B-frags hi           65536
#define WS_BLO   312384      // bf16 B-frags lo           65536

typedef short  short8  __attribute__((ext_vector_type(8)));
typedef float  floatx4 __attribute__((ext_vector_type(4)));

static __device__ __forceinline__ unsigned short f2bf(float x) {
    unsigned u = __float_as_uint(x);
    return (unsigned short)((u + 0x7fffu + ((u >> 16) & 1u)) >> 16);
}
static __device__ __forceinline__ float bf2f(unsigned short b) {
    return __uint_as_float(((unsigned)b) << 16);
}

// ---------------------------------------------------------------------------
// Fused prep (unchanged, verified).
// ---------------------------------------------------------------------------
__global__ __launch_bounds__(256) void prep_all(
        const float* __restrict__ w,
        float* __restrict__ wT, float* __restrict__ e2,
        short8* __restrict__ bhi, short8* __restrict__ blo,
        int* __restrict__ ctr) {
    int t = blockIdx.x * 256 + threadIdx.x;
    if (t < 32768) {
        int k = t & 1023, d4 = t >> 10;
        float4 v;
        v.x = w[(d4 * 4 + 0) * KK + k];
        v.y = w[(d4 * 4 + 1) * KK + k];
        v.z = w[(d4 * 4 + 2) * KK + k];
        v.w = w[(d4 * 4 + 3) * KK + k];
        *(float4*)(wT + (size_t)k * DD + d4 * 4) = v;
    } else if (t < 49152) {
        int u     = t - 32768;
        int lane  = u & 63;
        int chunk = (u >> 6) & 3;
        int ktile = u >> 8;
        int kcol  = ktile * 16 + (lane & 15);
        int d0    = chunk * 32 + (lane >> 4) * 8;
        short8 h, l;
#pragma unroll
        for (int j = 0; j < 8; ++j) {
            float wv = w[(size_t)(d0 + j) * KK + kcol];
            unsigned short hb = f2bf(wv);
            h[j] = (short)hb;
            l[j] = (short)f2bf(wv - bf2f(hb));
        }
        bhi[u] = h;
        blo[u] = l;
    } else if (t < 50176) {
        int k = t - 49152;
        if (k == 0) { ctr[0] = 0; ctr[1] = 0; }
        float acc = 0.0f;
        for (int d = 0; d < DD; ++d) {
            float v = w[d * KK + k];
            acc = __fadd_rn(acc, __fmul_rn(v, v));
        }
        e2[k] = acc;
    }
}

// ---------------------------------------------------------------------------
// Screen: r2/r4 kernel (215 µs control) + ONE change: a raw s_barrier per
// k-tile (NO vmcnt drain — register prefetch stays in flight). Purpose:
// keep the block's 4 waves tile-synchronized so their identical per-tile
// 8KB B-reads hit L1 instead of 4x-replaying through L2 (2.1 GB/dispatch
// ~= 62 µs of L2 BW at the 34.5 TB/s ceiling). Numerics untouched.
// ---------------------------------------------------------------------------
__global__ __launch_bounds__(256) void vq_screen(
        const float* __restrict__ x,
        const float* __restrict__ wT,
        const float* __restrict__ e2,
        const short8* __restrict__ bhi,
        const short8* __restrict__ blo,
        float* __restrict__ out,
        int* __restrict__ listA,
        int* __restrict__ listB,
        int* __restrict__ ctr) {
    __shared__ int sk1[4][32];

    const int tid  = threadIdx.x;
    const int wave = tid >> 6;
    const int lane = tid & 63;
    const int q    = lane >> 4;
    const int col  = lane & 15;

    const int b       = blockIdx.x >> 5;
    const int base_hw = (blockIdx.x & 31) * 128 + wave * 32;

    // A fragments: x[pixel][d = chunk*32 + q*8 + j], bf16 hi/lo split
    short8 a0h[4], a0l[4], a1h[4], a1l[4];
#pragma unroll
    for (int c = 0; c < 4; ++c) {
#pragma unroll
        for (int j = 0; j < 8; ++j) {
            int d = c * 32 + q * 8 + j;
            const float* xr = x + (size_t)(b * DD + d) * HWW + base_hw;
            float x0 = xr[col];
            float x1 = xr[16 + col];
            unsigned short h0 = f2bf(x0), h1 = f2bf(x1);
            a0h[c][j] = (short)h0;  a0l[c][j] = (short)f2bf(x0 - bf2f(h0));
            a1h[c][j] = (short)h1;  a1l[c][j] = (short)f2bf(x1 - bf2f(h1));
        }
    }

    float s1[8], s2[8], s3[8];
    int   c1[8], c2[8];
    float prevS[8];
    float prevE2 = 0.0f;
#pragma unroll
    for (int i = 0; i < 8; ++i) {
        s1[i] = INFINITY; s2[i] = INFINITY; s3[i] = INFINITY;
        c1[i] = 0; c2[i] = 0;
        prevS[i] = -INFINITY;          // fmaf(-2,-INF,e2) = +INF -> no-op
    }

    // Deferred top-3 update for tile `ktile` (state in prevS/prevE2).
    // FP value sequence identical to verified r5:
    //   med3(s,s1,s2) == min(s2, max(s, s1))  (exact selection, no rounding)
    //   med3(s,s2,s3) == min(s3, max(s, s2))
    auto top3_update = [&](int ktile) {
        const int kcur = ktile * 16 + col;
#pragma unroll
        for (int i = 0; i < 8; ++i) {
            float s = fmaf(-2.0f, prevS[i], prevE2);
            bool lt1 = s < s1[i];
            bool lt2 = s < s2[i];
            s3[i] = __builtin_amdgcn_fmed3f(s, s2[i], s3[i]);   // uses s2_old
            s2[i] = __builtin_amdgcn_fmed3f(s, s1[i], s2[i]);   // uses s1_old
            c2[i] = lt1 ? c1[i] : (lt2 ? kcur : c2[i]);
            s1[i] = fminf(s, s1[i]);
            c1[i] = lt1 ? kcur : c1[i];
        }
    };

    const short8* pbh = bhi + lane;
    const short8* pbl = blo + lane;

    // two named B-register sets (manual double-buffer, no copies)
    short8 hA0, hA1, hA2, hA3, lA0, lA1, lA2, lA3;   // set A
    short8 hB0, hB1, hB2, hB3, lB0, lB1, lB2, lB3;   // set B

    // tile 0 -> set A
    hA0 = pbh[0];   hA1 = pbh[64];  hA2 = pbh[128]; hA3 = pbh[192];
    lA0 = pbl[0];   lA1 = pbl[64];  lA2 = pbl[128]; lA3 = pbl[192];

#define MFMA_TILE(H0, H1, H2, H3, L0, L1, L2, L3)                              \
    {                                                                          \
        floatx4 p00 = {0.f,0.f,0.f,0.f}, p01 = {0.f,0.f,0.f,0.f};              \
        floatx4 p10 = {0.f,0.f,0.f,0.f}, p11 = {0.f,0.f,0.f,0.f};              \
        p00 = __builtin_amdgcn_mfma_f32_16x16x32_bf16(a0h[0], H0, p00, 0,0,0); \
        p01 = __builtin_amdgcn_mfma_f32_16x16x32_bf16(a0h[1], H1, p01, 0,0,0); \
        p00 = __builtin_amdgcn_mfma_f32_16x16x32_bf16(a0h[2], H2, p00, 0,0,0); \
        p01 = __builtin_amdgcn_mfma_f32_16x16x32_bf16(a0h[3], H3, p01, 0,0,0); \
        p00 = __builtin_amdgcn_mfma_f32_16x16x32_bf16(a0h[0], L0, p00, 0,0,0); \
        p01 = __builtin_amdgcn_mfma_f32_16x16x32_bf16(a0h[1], L1, p01, 0,0,0); \
        p00 = __builtin_amdgcn_mfma_f32_16x16x32_bf16(a0h[2], L2, p00, 0,0,0); \
        p01 = __builtin_amdgcn_mfma_f32_16x16x32_bf16(a0h[3], L3, p01, 0,0,0); \
        p00 = __builtin_amdgcn_mfma_f32_16x16x32_bf16(a0l[0], H0, p00, 0,0,0); \
        p01 = __builtin_amdgcn_mfma_f32_16x16x32_bf16(a0l[1], H1, p01, 0,0,0); \
        p00 = __builtin_amdgcn_mfma_f32_16x16x32_bf16(a0l[2], H2, p00, 0,0,0); \
        p01 = __builtin_amdgcn_mfma_f32_16x16x32_bf16(a0l[3], H3, p01, 0,0,0); \
        p10 = __builtin_amdgcn_mfma_f32_16x16x32_bf16(a1h[0], H0, p10, 0,0,0); \
        p11 = __builtin_amdgcn_mfma_f32_16x16x32_bf16(a1h[1], H1, p11, 0,0,0); \
        p10 = __builtin_amdgcn_mfma_f32_16x16x32_bf16(a1h[2], H2, p10, 0,0,0); \
        p11 = __builtin_amdgcn_mfma_f32_16x16x32_bf16(a1h[3], H3, p11, 0,0,0); \
        p10 = __builtin_amdgcn_mfma_f32_16x16x32_bf16(a1h[0], L0, p10, 0,0,0); \
        p11 = __builtin_amdgcn_mfma_f32_16x16x32_bf16(a1h[1], L1, p11, 0,0,0); \
        p10 = __builtin_amdgcn_mfma_f32_16x16x32_bf16(a1h[2], L2, p10, 0,0,0); \
        p11 = __builtin_amdgcn_mfma_f32_16x16x32_bf16(a1h[3], L3, p11, 0,0,0); \
        p10 = __builtin_amdgcn_mfma_f32_16x16x32_bf16(a1l[0], H0, p10, 0,0,0); \
        p11 = __builtin_amdgcn_mfma_f32_16x16x32_bf16(a1l[1], H1, p11, 0,0,0); \
        p10 = __builtin_amdgcn_mfma_f32_16x16x32_bf16(a1l[2], H2, p10, 0,0,0); \
        p11 = __builtin_amdgcn_mfma_f32_16x16x32_bf16(a1l[3], H3, p11, 0,0,0); \
        prevS[0] = p00[0] + p01[0];                                            \
        prevS[1] = p00[1] + p01[1];                                            \
        prevS[2] = p00[2] + p01[2];                                            \
        prevS[3] = p00[3] + p01[3];                                            \
        prevS[4] = p10[0] + p11[0];                                            \
        prevS[5] = p10[1] + p11[1];                                            \
        prevS[6] = p10[2] + p11[2];                                            \
        prevS[7] = p10[3] + p11[3];                                            \
        prevE2   = e2v;                                                        \
    }

    for (int kt = 0; kt < 64; kt += 2) {
        // ---- half 1: compute tile kt (set A), prefetch kt+1 -> set B ----
        {
            // tile-sync the 4 waves (raw barrier: NO waitcnt drain, register
            // prefetch stays in flight) -> same-tile B reads hit L1
            __builtin_amdgcn_s_barrier();
            const int nb = (kt + 1) * 256;          // kt+1 <= 63: in bounds
            hB0 = pbh[nb];       hB1 = pbh[nb + 64];
            hB2 = pbh[nb + 128]; hB3 = pbh[nb + 192];
            lB0 = pbl[nb];       lB1 = pbl[nb + 64];
            lB2 = pbl[nb + 128]; lB3 = pbl[nb + 192];
            float e2v = e2[kt * 16 + col];
            top3_update(kt - 1);                    // overlaps load latency
            MFMA_TILE(hA0, hA1, hA2, hA3, lA0, lA1, lA2, lA3)
        }
        // ---- half 2: compute tile kt+1 (set B), prefetch kt+2 -> set A ----
        {
            __builtin_amdgcn_s_barrier();
            const int nb = ((kt + 2) & 63) * 256;   // kt=62 wraps to 0 (unused)
            hA0 = pbh[nb];       hA1 = pbh[nb + 64];
            hA2 = pbh[nb + 128]; hA3 = pbh[nb + 192];
            lA0 = pbl[nb];       lA1 = pbl[nb + 64];
            lA2 = pbl[nb + 128]; lA3 = pbl[nb + 192];
            float e2v = e2[(kt + 1) * 16 + col];
            top3_update(kt);
            MFMA_TILE(hB0, hB1, hB2, hB3, lB0, lB1, lB2, lB3)
        }
    }
    top3_update(63);       // drain the deferred pipeline
#undef MFMA_TILE

    // Butterfly merge of sorted top-3 states across the 16 k-columns (verified r5).
#pragma unroll
    for (int off = 1; off < 16; off <<= 1) {
#pragma unroll
        for (int i = 0; i < 8; ++i) {
            float o1 = __shfl_xor(s1[i], off);
            float o2 = __shfl_xor(s2[i], off);
            float o3 = __shfl_xor(s3[i], off);
            int   ok1 = __shfl_xor(c1[i], off);
            int   ok2 = __shfl_xor(c2[i], off);
            bool afirst = (s1[i] < o1) || (s1[i] == o1 && c1[i] < ok1);
            float n1, n2, n3; int nk1, nk2;
            if (afirst) {
                bool asec = (s2[i] < o1) || (s2[i] == o1 && c2[i] < ok1);
                n1 = s1[i]; nk1 = c1[i];
                n2 = asec ? s2[i] : o1;  nk2 = asec ? c2[i] : ok1;
                n3 = asec ? fminf(s3[i], o1) : fminf(s2[i], o2);
            } else {
                bool bsec = (o2 < s1[i]) || (o2 == s1[i] && ok2 < c1[i]);
                n1 = o1; nk1 = ok1;
                n2 = bsec ? o2 : s1[i];  nk2 = bsec ? ok2 : c1[i];
                n3 = bsec ? fminf(o3, s1[i]) : fminf(o2, s2[i]);
            }
            s1[i] = n1; s2[i] = n2; s3[i] = n3; c1[i] = nk1; c2[i] = nk2;
        }
    }

    // Publish (verified r5)
#pragma unroll
    for (int g = 0; g < 2; ++g) {
#pragma unroll
        for (int r = 0; r < 4; ++r) {
            if (col == r) {
                const int i = g * 4 + r;
                int plocal = g * 16 + q * 4 + r;
                int hwp    = base_hw + plocal;
                int Pg     = b * HWW + hwp;
                out[(size_t)DD * NPIX + Pg] = (float)c1[i];
                sk1[wave][plocal] = c1[i];
                float g12 = s2[i] - s1[i];
                float g13 = s3[i] - s1[i];
                if (g12 <= EPS) {
                    if (g13 > EPS) {
                        int idx = atomicAdd(&ctr[0], 1);
                        if (idx < CAPA) {
                            listA[3 * idx + 0] = Pg;
                            listA[3 * idx + 1] = c1[i];
                            listA[3 * idx + 2] = c2[i];
                        }
                    } else {
                        int idx = atomicAdd(&ctr[1], 1);
                        if (idx < CAPB) listB[idx] = Pg;
                    }
                }
            }
        }
    }
    __syncthreads();

    // Gather epilogue (verified r3-r5)
    {
        const int p_lo = lane & 15;
        const int dgrp = lane >> 4;
#pragma unroll
        for (int half = 0; half < 2; ++half) {
            const int plocal = half * 16 + p_lo;
            const int kk     = sk1[wave][plocal];
            const int hwp    = base_hw + plocal;
            const float* wrow = wT + (size_t)kk * DD;
#pragma unroll
            for (int i = 0; i < 32; ++i) {
                int d = i * 4 + dgrp;
                out[(size_t)(b * DD + d) * HWW + hwp] = wrow[d];
            }
        }
    }
}

// ---------------------------------------------------------------------------
// Fused resolve: r4's verified vq_scan + vq_pair bodies in ONE kernel
// (saves a launch; both loops are independent per-entry, no cross deps).
//  - listB scans: pixel staged in wave-private LDS (fixes rule-#20 scratch).
//  - listA pairs: skip rewrite when exact winner == screen's published kA.
// ---------------------------------------------------------------------------
__global__ __launch_bounds__(256) void vq_resolve(
        const float* __restrict__ x,
        const float* __restrict__ wT,
        const float* __restrict__ e2,
        const int* __restrict__ listA,
        const int* __restrict__ listB,
        const int* __restrict__ ctr,
        float* __restrict__ out) {
    __shared__ float sxv[4][DD];
    const int nA = min(ctr[0], CAPA);
    const int nB = min(ctr[1], CAPB);
    const int tid   = threadIdx.x;
    const int lane  = tid & 63;
    const int lwave = tid >> 6;
    const int wave  = (blockIdx.x * 256 + tid) >> 6;
    const int NW    = (gridDim.x * 256) >> 6;
    const int NT    = gridDim.x * 256;

    // ---- full scans (rare) ----
    for (int j = wave; j < nB; j += NW) {
        const int p  = listB[j];
        const int b  = p >> 12;
        const int hw = p & (HWW - 1);
        const float* xp = x + (size_t)b * DD * HWW + hw;

        // wave-cooperative stage of the pixel's 128 channels into LDS
        sxv[lwave][lane]      = xp[(size_t)lane * HWW];
        sxv[lwave][lane + 64] = xp[(size_t)(lane + 64) * HWW];
        __builtin_amdgcn_wave_barrier();   // in-wave ordering (waitcnt via mem dep)

        const float* xv = sxv[lwave];
        float x2 = 0.0f;
        for (int d = 0; d < DD; ++d)
            x2 = __fadd_rn(x2, __fmul_rn(xv[d], xv[d]));

        unsigned long long best = ~0ull;
        for (int kk = 0; kk < 16; ++kk) {
            const int k = lane * 16 + kk;
            const float* wk = wT + (size_t)k * DD;
            float a = 0.0f;
#pragma unroll 4
            for (int d = 0; d < DD; ++d)
                a = __fadd_rn(a, __fmul_rn(xv[d], wk[d]));
            float d2 = __fadd_rn(__fsub_rn(x2, 2.0f * a), e2[k]);
            unsigned long long c =
                ((unsigned long long)__float_as_uint(d2) << 32) | (unsigned)k;
            best = best < c ? best : c;
        }
#pragma unroll
        for (int off = 32; off; off >>= 1) {
            unsigned long long o = __shfl_xor(best, off);
            best = best < o ? best : o;
        }
        const int kwin  = (int)(best & 0xffffffffu);
        const int guess = (int)out[(size_t)DD * NPIX + p];   // screen's c1
        if (kwin != guess) {
            if (lane == 0) out[(size_t)DD * NPIX + p] = (float)kwin;
            const float* wb = wT + (size_t)kwin * DD;
            float* op = out + (size_t)b * DD * HWW + hw;
            op[(size_t)lane * HWW]        = wb[lane];
            op[(size_t)(lane + 64) * HWW] = wb[lane + 64];
        }
        __builtin_amdgcn_wave_barrier();   // all reads done before next stage
    }

    // ---- pair resolves (thread per entry, CU-spread mapping) ----
    for (int i = blockIdx.x + tid * gridDim.x; i < nA; i += NT) {
        const int p  = listA[3 * i + 0];
        const int kA = listA[3 * i + 1];
        const int kB = listA[3 * i + 2];
        const int b  = p >> 12;
        const int hw = p & (HWW - 1);
        const float* xp = x + (size_t)b * DD * HWW + hw;
        const float* wa = wT + (size_t)kA * DD;
        const float* wb = wT + (size_t)kB * DD;
        float x2 = 0.0f, aa = 0.0f, ab = 0.0f;
#pragma unroll 4
        for (int d = 0; d < DD; ++d) {
            float xd = xp[(size_t)d * HWW];
            x2 = __fadd_rn(x2, __fmul_rn(xd, xd));
            aa = __fadd_rn(aa, __fmul_rn(xd, wa[d]));
            ab = __fadd_rn(ab, __fmul_rn(xd, wb[d]));
        }
        float dA = __fadd_rn(__fsub_rn(x2, 2.0f * aa), e2[kA]);
        float dB = __fadd_rn(__fsub_rn(x2, 2.0f * ab), e2[kB]);
        const int kwin = (dA < dB || (dA == dB && kA < kB)) ? kA : kB;
        if (kwin != kA) {   // screen already published kA's idx + row
            out[(size_t)DD * NPIX + p] = (float)kwin;
            const float* ww = wT + (size_t)kwin * DD;
            float* op = out + (size_t)b * DD * HWW + hw;
#pragma unroll 8
            for (int d = 0; d < DD; ++d) op[(size_t)d * HWW] = ww[d];
        }
    }
}

extern "C" void kernel_launch(void* const* d_in, const int* in_sizes, int n_in,
                              void* d_out, int out_size, void* d_ws, size_t ws_size,
                              hipStream_t stream) {
    const float* x = (const float*)d_in[0];
    const float* w = (const float*)d_in[1];
    float* out = (float*)d_out;
    float* wsf = (float*)d_ws;

    float*  wT    = wsf + WS_WT;
    float*  e2    = wsf + WS_E2;
    int*    ctr   = (int*)(wsf + WS_CTR);
    int*    listA = (int*)(wsf + WS_LISTA);
    int*    listB = (int*)(wsf + WS_LISTB);
    short8* bhi   = (short8*)(wsf + WS_BHI);
    short8* blo   = (short8*)(wsf + WS_BLO);

    prep_all  <<<dim3(196),  dim3(256), 0, stream>>>(w, wT, e2, bhi, blo, ctr);
    vq_screen <<<dim3(1024), dim3(256), 0, stream>>>(x, wT, e2, bhi, blo, out,
                                                     listA, listB, ctr);
    vq_resolve<<<dim3(256),  dim3(256), 0, stream>>>(x, wT, e2, listA, listB,
                                                     ctr, out);
}

// Round 6
// 374.268 us; speedup vs baseline: 1.0524x; 1.0524x over previous
//
#include <hip/hip_runtime.h>
#include <math.h>

#define DD   128
#define KK   1024
#define HWW  4096
#define NPIX 131072
#define EPS  1.5e-4f        // >= 3.8x the ~3.9e-5 worst-case pair-comparison bound
#define CAPA 32768
#define CAPB 8192

// ws layout in float slots:
#define WS_WT    0           // fp32 wT[K][D]            131072
#define WS_E2    131072      // fp32 e2[K]                 1024
#define WS_CTR   132096      // int ctrA, ctrB (pad 64)
#define WS_LISTA 132160      // int {p,k1,k2} x CAPA      98304
#define WS_LISTB 230464      // int {p} x CAPB            16384
#define WS_BHI   246848      // bf16 B-frags hi           65536
#define WS_BLO   312384      // bf16 B-frags lo           65536

typedef short  short8  __attribute__((ext_vector_type(8)));
typedef float  floatx4 __attribute__((ext_vector_type(4)));

static __device__ __forceinline__ unsigned short f2bf(float x) {
    unsigned u = __float_as_uint(x);
    return (unsigned short)((u + 0x7fffu + ((u >> 16) & 1u)) >> 16);
}
static __device__ __forceinline__ float bf2f(unsigned short b) {
    return __uint_as_float(((unsigned)b) << 16);
}

// ---------------------------------------------------------------------------
// Fused prep (unchanged, verified — control).
// ---------------------------------------------------------------------------
__global__ __launch_bounds__(256) void prep_all(
        const float* __restrict__ w,
        float* __restrict__ wT, float* __restrict__ e2,
        short8* __restrict__ bhi, short8* __restrict__ blo,
        int* __restrict__ ctr) {
    int t = blockIdx.x * 256 + threadIdx.x;
    if (t < 32768) {
        int k = t & 1023, d4 = t >> 10;
        float4 v;
        v.x = w[(d4 * 4 + 0) * KK + k];
        v.y = w[(d4 * 4 + 1) * KK + k];
        v.z = w[(d4 * 4 + 2) * KK + k];
        v.w = w[(d4 * 4 + 3) * KK + k];
        *(float4*)(wT + (size_t)k * DD + d4 * 4) = v;
    } else if (t < 49152) {
        int u     = t - 32768;
        int lane  = u & 63;
        int chunk = (u >> 6) & 3;
        int ktile = u >> 8;
        int kcol  = ktile * 16 + (lane & 15);
        int d0    = chunk * 32 + (lane >> 4) * 8;
        short8 h, l;
#pragma unroll
        for (int j = 0; j < 8; ++j) {
            float wv = w[(size_t)(d0 + j) * KK + kcol];
            unsigned short hb = f2bf(wv);
            h[j] = (short)hb;
            l[j] = (short)f2bf(wv - bf2f(hb));
        }
        bhi[u] = h;
        blo[u] = l;
    } else if (t < 50176) {
        int k = t - 49152;
        if (k == 0) { ctr[0] = 0; ctr[1] = 0; }
        float acc = 0.0f;
        for (int d = 0; d < DD; ++d) {
            float v = w[d * KK + k];
            acc = __fadd_rn(acc, __fmul_rn(v, v));
        }
        e2[k] = acc;
    }
}

// ---------------------------------------------------------------------------
// Screen: EXACT r2 kernel (215 µs best-known; r5's s_barrier removed) with
// ONE change: __launch_bounds__(256, 2). Theory: bare launch_bounds lets the
// allocator cap VGPRs at 128 (4 waves/EU target) and spill ~47 dw/thread
// (the persistent +48 MB WRITE_SIZE anomaly); achieved occupancy is ~2
// waves/SIMD regardless, so the spill buys nothing and its in-loop restores
// (L2/L3 latency) are the unexplained ~85% stall. (256,2) raises the cap to
// 256 regs == where we actually run, eliminating the spill.
// ---------------------------------------------------------------------------
__global__ __launch_bounds__(256, 2) void vq_screen(
        const float* __restrict__ x,
        const float* __restrict__ wT,
        const float* __restrict__ e2,
        const short8* __restrict__ bhi,
        const short8* __restrict__ blo,
        float* __restrict__ out,
        int* __restrict__ listA,
        int* __restrict__ listB,
        int* __restrict__ ctr) {
    __shared__ int sk1[4][32];

    const int tid  = threadIdx.x;
    const int wave = tid >> 6;
    const int lane = tid & 63;
    const int q    = lane >> 4;
    const int col  = lane & 15;

    const int b       = blockIdx.x >> 5;
    const int base_hw = (blockIdx.x & 31) * 128 + wave * 32;

    // A fragments: x[pixel][d = chunk*32 + q*8 + j], bf16 hi/lo split
    short8 a0h[4], a0l[4], a1h[4], a1l[4];
#pragma unroll
    for (int c = 0; c < 4; ++c) {
#pragma unroll
        for (int j = 0; j < 8; ++j) {
            int d = c * 32 + q * 8 + j;
            const float* xr = x + (size_t)(b * DD + d) * HWW + base_hw;
            float x0 = xr[col];
            float x1 = xr[16 + col];
            unsigned short h0 = f2bf(x0), h1 = f2bf(x1);
            a0h[c][j] = (short)h0;  a0l[c][j] = (short)f2bf(x0 - bf2f(h0));
            a1h[c][j] = (short)h1;  a1l[c][j] = (short)f2bf(x1 - bf2f(h1));
        }
    }

    float s1[8], s2[8], s3[8];
    int   c1[8], c2[8];
    float prevS[8];
    float prevE2 = 0.0f;
#pragma unroll
    for (int i = 0; i < 8; ++i) {
        s1[i] = INFINITY; s2[i] = INFINITY; s3[i] = INFINITY;
        c1[i] = 0; c2[i] = 0;
        prevS[i] = -INFINITY;          // fmaf(-2,-INF,e2) = +INF -> no-op
    }

    // Deferred top-3 update for tile `ktile` (state in prevS/prevE2).
    // FP value sequence identical to verified r5:
    //   med3(s,s1,s2) == min(s2, max(s, s1))  (exact selection, no rounding)
    //   med3(s,s2,s3) == min(s3, max(s, s2))
    auto top3_update = [&](int ktile) {
        const int kcur = ktile * 16 + col;
#pragma unroll
        for (int i = 0; i < 8; ++i) {
            float s = fmaf(-2.0f, prevS[i], prevE2);
            bool lt1 = s < s1[i];
            bool lt2 = s < s2[i];
            s3[i] = __builtin_amdgcn_fmed3f(s, s2[i], s3[i]);   // uses s2_old
            s2[i] = __builtin_amdgcn_fmed3f(s, s1[i], s2[i]);   // uses s1_old
            c2[i] = lt1 ? c1[i] : (lt2 ? kcur : c2[i]);
            s1[i] = fminf(s, s1[i]);
            c1[i] = lt1 ? kcur : c1[i];
        }
    };

    const short8* pbh = bhi + lane;
    const short8* pbl = blo + lane;

    // two named B-register sets (manual double-buffer, no copies)
    short8 hA0, hA1, hA2, hA3, lA0, lA1, lA2, lA3;   // set A
    short8 hB0, hB1, hB2, hB3, lB0, lB1, lB2, lB3;   // set B

    // tile 0 -> set A
    hA0 = pbh[0];   hA1 = pbh[64];  hA2 = pbh[128]; hA3 = pbh[192];
    lA0 = pbl[0];   lA1 = pbl[64];  lA2 = pbl[128]; lA3 = pbl[192];

#define MFMA_TILE(H0, H1, H2, H3, L0, L1, L2, L3)                              \
    {                                                                          \
        floatx4 p00 = {0.f,0.f,0.f,0.f}, p01 = {0.f,0.f,0.f,0.f};              \
        floatx4 p10 = {0.f,0.f,0.f,0.f}, p11 = {0.f,0.f,0.f,0.f};              \
        p00 = __builtin_amdgcn_mfma_f32_16x16x32_bf16(a0h[0], H0, p00, 0,0,0); \
        p01 = __builtin_amdgcn_mfma_f32_16x16x32_bf16(a0h[1], H1, p01, 0,0,0); \
        p00 = __builtin_amdgcn_mfma_f32_16x16x32_bf16(a0h[2], H2, p00, 0,0,0); \
        p01 = __builtin_amdgcn_mfma_f32_16x16x32_bf16(a0h[3], H3, p01, 0,0,0); \
        p00 = __builtin_amdgcn_mfma_f32_16x16x32_bf16(a0h[0], L0, p00, 0,0,0); \
        p01 = __builtin_amdgcn_mfma_f32_16x16x32_bf16(a0h[1], L1, p01, 0,0,0); \
        p00 = __builtin_amdgcn_mfma_f32_16x16x32_bf16(a0h[2], L2, p00, 0,0,0); \
        p01 = __builtin_amdgcn_mfma_f32_16x16x32_bf16(a0h[3], L3, p01, 0,0,0); \
        p00 = __builtin_amdgcn_mfma_f32_16x16x32_bf16(a0l[0], H0, p00, 0,0,0); \
        p01 = __builtin_amdgcn_mfma_f32_16x16x32_bf16(a0l[1], H1, p01, 0,0,0); \
        p00 = __builtin_amdgcn_mfma_f32_16x16x32_bf16(a0l[2], H2, p00, 0,0,0); \
        p01 = __builtin_amdgcn_mfma_f32_16x16x32_bf16(a0l[3], H3, p01, 0,0,0); \
        p10 = __builtin_amdgcn_mfma_f32_16x16x32_bf16(a1h[0], H0, p10, 0,0,0); \
        p11 = __builtin_amdgcn_mfma_f32_16x16x32_bf16(a1h[1], H1, p11, 0,0,0); \
        p10 = __builtin_amdgcn_mfma_f32_16x16x32_bf16(a1h[2], H2, p10, 0,0,0); \
        p11 = __builtin_amdgcn_mfma_f32_16x16x32_bf16(a1h[3], H3, p11, 0,0,0); \
        p10 = __builtin_amdgcn_mfma_f32_16x16x32_bf16(a1h[0], L0, p10, 0,0,0); \
        p11 = __builtin_amdgcn_mfma_f32_16x16x32_bf16(a1h[1], L1, p11, 0,0,0); \
        p10 = __builtin_amdgcn_mfma_f32_16x16x32_bf16(a1h[2], L2, p10, 0,0,0); \
        p11 = __builtin_amdgcn_mfma_f32_16x16x32_bf16(a1h[3], L3, p11, 0,0,0); \
        p10 = __builtin_amdgcn_mfma_f32_16x16x32_bf16(a1l[0], H0, p10, 0,0,0); \
        p11 = __builtin_amdgcn_mfma_f32_16x16x32_bf16(a1l[1], H1, p11, 0,0,0); \
        p10 = __builtin_amdgcn_mfma_f32_16x16x32_bf16(a1l[2], H2, p10, 0,0,0); \
        p11 = __builtin_amdgcn_mfma_f32_16x16x32_bf16(a1l[3], H3, p11, 0,0,0); \
        prevS[0] = p00[0] + p01[0];                                            \
        prevS[1] = p00[1] + p01[1];                                            \
        prevS[2] = p00[2] + p01[2];                                            \
        prevS[3] = p00[3] + p01[3];                                            \
        prevS[4] = p10[0] + p11[0];                                            \
        prevS[5] = p10[1] + p11[1];                                            \
        prevS[6] = p10[2] + p11[2];                                            \
        prevS[7] = p10[3] + p11[3];                                            \
        prevE2   = e2v;                                                        \
    }

    for (int kt = 0; kt < 64; kt += 2) {
        // ---- half 1: compute tile kt (set A), prefetch kt+1 -> set B ----
        {
            const int nb = (kt + 1) * 256;          // kt+1 <= 63: in bounds
            hB0 = pbh[nb];       hB1 = pbh[nb + 64];
            hB2 = pbh[nb + 128]; hB3 = pbh[nb + 192];
            lB0 = pbl[nb];       lB1 = pbl[nb + 64];
            lB2 = pbl[nb + 128]; lB3 = pbl[nb + 192];
            float e2v = e2[kt * 16 + col];
            top3_update(kt - 1);                    // overlaps load latency
            MFMA_TILE(hA0, hA1, hA2, hA3, lA0, lA1, lA2, lA3)
        }
        // ---- half 2: compute tile kt+1 (set B), prefetch kt+2 -> set A ----
        {
            const int nb = ((kt + 2) & 63) * 256;   // kt=62 wraps to 0 (unused)
            hA0 = pbh[nb];       hA1 = pbh[nb + 64];
            hA2 = pbh[nb + 128]; hA3 = pbh[nb + 192];
            lA0 = pbl[nb];       lA1 = pbl[nb + 64];
            lA2 = pbl[nb + 128]; lA3 = pbl[nb + 192];
            float e2v = e2[(kt + 1) * 16 + col];
            top3_update(kt);
            MFMA_TILE(hB0, hB1, hB2, hB3, lB0, lB1, lB2, lB3)
        }
    }
    top3_update(63);       // drain the deferred pipeline
#undef MFMA_TILE

    // Butterfly merge of sorted top-3 states across the 16 k-columns (verified r5).
#pragma unroll
    for (int off = 1; off < 16; off <<= 1) {
#pragma unroll
        for (int i = 0; i < 8; ++i) {
            float o1 = __shfl_xor(s1[i], off);
            float o2 = __shfl_xor(s2[i], off);
            float o3 = __shfl_xor(s3[i], off);
            int   ok1 = __shfl_xor(c1[i], off);
            int   ok2 = __shfl_xor(c2[i], off);
            bool afirst = (s1[i] < o1) || (s1[i] == o1 && c1[i] < ok1);
            float n1, n2, n3; int nk1, nk2;
            if (afirst) {
                bool asec = (s2[i] < o1) || (s2[i] == o1 && c2[i] < ok1);
                n1 = s1[i]; nk1 = c1[i];
                n2 = asec ? s2[i] : o1;  nk2 = asec ? c2[i] : ok1;
                n3 = asec ? fminf(s3[i], o1) : fminf(s2[i], o2);
            } else {
                bool bsec = (o2 < s1[i]) || (o2 == s1[i] && ok2 < c1[i]);
                n1 = o1; nk1 = ok1;
                n2 = bsec ? o2 : s1[i];  nk2 = bsec ? ok2 : c1[i];
                n3 = bsec ? fminf(o3, s1[i]) : fminf(o2, s2[i]);
            }
            s1[i] = n1; s2[i] = n2; s3[i] = n3; c1[i] = nk1; c2[i] = nk2;
        }
    }

    // Publish (verified r5)
#pragma unroll
    for (int g = 0; g < 2; ++g) {
#pragma unroll
        for (int r = 0; r < 4; ++r) {
            if (col == r) {
                const int i = g * 4 + r;
                int plocal = g * 16 + q * 4 + r;
                int hwp    = base_hw + plocal;
                int Pg     = b * HWW + hwp;
                out[(size_t)DD * NPIX + Pg] = (float)c1[i];
                sk1[wave][plocal] = c1[i];
                float g12 = s2[i] - s1[i];
                float g13 = s3[i] - s1[i];
                if (g12 <= EPS) {
                    if (g13 > EPS) {
                        int idx = atomicAdd(&ctr[0], 1);
                        if (idx < CAPA) {
                            listA[3 * idx + 0] = Pg;
                            listA[3 * idx + 1] = c1[i];
                            listA[3 * idx + 2] = c2[i];
                        }
                    } else {
                        int idx = atomicAdd(&ctr[1], 1);
                        if (idx < CAPB) listB[idx] = Pg;
                    }
                }
            }
        }
    }
    __syncthreads();

    // Gather epilogue (verified r3-r5)
    {
        const int p_lo = lane & 15;
        const int dgrp = lane >> 4;
#pragma unroll
        for (int half = 0; half < 2; ++half) {
            const int plocal = half * 16 + p_lo;
            const int kk     = sk1[wave][plocal];
            const int hwp    = base_hw + plocal;
            const float* wrow = wT + (size_t)kk * DD;
#pragma unroll
            for (int i = 0; i < 32; ++i) {
                int d = i * 4 + dgrp;
                out[(size_t)(b * DD + d) * HWW + hwp] = wrow[d];
            }
        }
    }
}

// ---------------------------------------------------------------------------
// Fused resolve (r5 version, verified — control): listB wave-scans with
// LDS-staged pixel; listA pair resolves with conditional rewrite.
// ---------------------------------------------------------------------------
__global__ __launch_bounds__(256) void vq_resolve(
        const float* __restrict__ x,
        const float* __restrict__ wT,
        const float* __restrict__ e2,
        const int* __restrict__ listA,
        const int* __restrict__ listB,
        const int* __restrict__ ctr,
        float* __restrict__ out) {
    __shared__ float sxv[4][DD];
    const int nA = min(ctr[0], CAPA);
    const int nB = min(ctr[1], CAPB);
    const int tid   = threadIdx.x;
    const int lane  = tid & 63;
    const int lwave = tid >> 6;
    const int wave  = (blockIdx.x * 256 + tid) >> 6;
    const int NW    = (gridDim.x * 256) >> 6;
    const int NT    = gridDim.x * 256;

    // ---- full scans (rare) ----
    for (int j = wave; j < nB; j += NW) {
        const int p  = listB[j];
        const int b  = p >> 12;
        const int hw = p & (HWW - 1);
        const float* xp = x + (size_t)b * DD * HWW + hw;

        // wave-cooperative stage of the pixel's 128 channels into LDS
        sxv[lwave][lane]      = xp[(size_t)lane * HWW];
        sxv[lwave][lane + 64] = xp[(size_t)(lane + 64) * HWW];
        __builtin_amdgcn_wave_barrier();   // in-wave ordering (waitcnt via mem dep)

        const float* xv = sxv[lwave];
        float x2 = 0.0f;
        for (int d = 0; d < DD; ++d)
            x2 = __fadd_rn(x2, __fmul_rn(xv[d], xv[d]));

        unsigned long long best = ~0ull;
        for (int kk = 0; kk < 16; ++kk) {
            const int k = lane * 16 + kk;
            const float* wk = wT + (size_t)k * DD;
            float a = 0.0f;
#pragma unroll 4
            for (int d = 0; d < DD; ++d)
                a = __fadd_rn(a, __fmul_rn(xv[d], wk[d]));
            float d2 = __fadd_rn(__fsub_rn(x2, 2.0f * a), e2[k]);
            unsigned long long c =
                ((unsigned long long)__float_as_uint(d2) << 32) | (unsigned)k;
            best = best < c ? best : c;
        }
#pragma unroll
        for (int off = 32; off; off >>= 1) {
            unsigned long long o = __shfl_xor(best, off);
            best = best < o ? best : o;
        }
        const int kwin  = (int)(best & 0xffffffffu);
        const int guess = (int)out[(size_t)DD * NPIX + p];   // screen's c1
        if (kwin != guess) {
            if (lane == 0) out[(size_t)DD * NPIX + p] = (float)kwin;
            const float* wb = wT + (size_t)kwin * DD;
            float* op = out + (size_t)b * DD * HWW + hw;
            op[(size_t)lane * HWW]        = wb[lane];
            op[(size_t)(lane + 64) * HWW] = wb[lane + 64];
        }
        __builtin_amdgcn_wave_barrier();   // all reads done before next stage
    }

    // ---- pair resolves (thread per entry, CU-spread mapping) ----
    for (int i = blockIdx.x + tid * gridDim.x; i < nA; i += NT) {
        const int p  = listA[3 * i + 0];
        const int kA = listA[3 * i + 1];
        const int kB = listA[3 * i + 2];
        const int b  = p >> 12;
        const int hw = p & (HWW - 1);
        const float* xp = x + (size_t)b * DD * HWW + hw;
        const float* wa = wT + (size_t)kA * DD;
        const float* wb = wT + (size_t)kB * DD;
        float x2 = 0.0f, aa = 0.0f, ab = 0.0f;
#pragma unroll 4
        for (int d = 0; d < DD; ++d) {
            float xd = xp[(size_t)d * HWW];
            x2 = __fadd_rn(x2, __fmul_rn(xd, xd));
            aa = __fadd_rn(aa, __fmul_rn(xd, wa[d]));
            ab = __fadd_rn(ab, __fmul_rn(xd, wb[d]));
        }
        float dA = __fadd_rn(__fsub_rn(x2, 2.0f * aa), e2[kA]);
        float dB = __fadd_rn(__fsub_rn(x2, 2.0f * ab), e2[kB]);
        const int kwin = (dA < dB || (dA == dB && kA < kB)) ? kA : kB;
        if (kwin != kA) {   // screen already published kA's idx + row
            out[(size_t)DD * NPIX + p] = (float)kwin;
            const float* ww = wT + (size_t)kwin * DD;
            float* op = out + (size_t)b * DD * HWW + hw;
#pragma unroll 8
            for (int d = 0; d < DD; ++d) op[(size_t)d * HWW] = ww[d];
        }
    }
}

extern "C" void kernel_launch(void* const* d_in, const int* in_sizes, int n_in,
                              void* d_out, int out_size, void* d_ws, size_t ws_size,
                              hipStream_t stream) {
    const float* x = (const float*)d_in[0];
    const float* w = (const float*)d_in[1];
    float* out = (float*)d_out;
    float* wsf = (float*)d_ws;

    float*  wT    = wsf + WS_WT;
    float*  e2    = wsf + WS_E2;
    int*    ctr   = (int*)(wsf + WS_CTR);
    int*    listA = (int*)(wsf + WS_LISTA);
    int*    listB = (int*)(wsf + WS_LISTB);
    short8* bhi   = (short8*)(wsf + WS_BHI);
    short8* blo   = (short8*)(wsf + WS_BLO);

    prep_all  <<<dim3(196),  dim3(256), 0, stream>>>(w, wT, e2, bhi, blo, ctr);
    vq_screen <<<dim3(1024), dim3(256), 0, stream>>>(x, wT, e2, bhi, blo, out,
                                                     listA, listB, ctr);
    vq_resolve<<<dim3(256),  dim3(256), 0, stream>>>(x, wT, e2, listA, listB,
                                                     ctr, out);
}